// Round 9
// baseline (40.940 us; speedup 1.0000x reference)
//
#include <hip/hip_runtime.h>
#include <hip/hip_bf16.h>

#define NBINS 10
#define C 128
#define U 8           // pairs per wave (one-shot: all loads issued up front)
#define NREP 64       // gbins replicas (de-contend device-scope atomics)
#define REPSTRIDE 32  // u64 slots per replica (30 used, padded)

// d_ws layout: NREP replicas of [0..9] counts, [10..19] sum_conf (32.32 fixed),
//              [20..29] sum_acc  -- each replica REPSTRIDE u64 slots.

__global__ __launch_bounds__(256) void ece_main_kernel(
    const float* __restrict__ logits, const int* __restrict__ targets,
    unsigned long long* __restrict__ gbins, int N) {
  __shared__ unsigned long long sbins[3 * NBINS];
  const int tid = threadIdx.x;
  for (int i = tid; i < 3 * NBINS; i += blockDim.x) sbins[i] = 0ull;
  __syncthreads();

  const int lane = tid & 63;
  const int half = lane >> 5;   // which row of each pair this lane works on
  const int hl = lane & 31;     // lane index within the 32-lane half
  const int wavesPerBlock = blockDim.x >> 6;
  const int wid = blockIdx.x * wavesPerBlock + (tid >> 6);
  const int nwaves = gridDim.x * wavesPerBlock;

  const int npairs = N >> 1;

  // one-shot: grid sized so each wave runs this loop exactly once, with all
  // U=8 float4 loads (8 KiB/wave) issued before any dependent compute.
  for (int p0 = wid * U; p0 < npairs; p0 += nwaves * U) {
    float4 v[U];
    int pp[U];
    int tg[U];
    #pragma unroll
    for (int u = 0; u < U; ++u) {
      const int p = p0 + u;
      pp[u] = p < npairs ? p : npairs - 1;
      v[u] = *reinterpret_cast<const float4*>(
          logits + (size_t)pp[u] * (2 * C) + half * C + hl * 4);
    }
    // targets early (2 lanes/wave); latency hides under the reduce chains
    if (hl == 0) {
      #pragma unroll
      for (int u = 0; u < U; ++u) tg[u] = targets[pp[u] * 2 + half];
    }

    // exps issue as loads land (no max-subtract: |logit| <~ 6 for N(0,1);
    // conf = exp(m)/sum(exp(x)) is mathematically identical)
    float s[U];
    #pragma unroll
    for (int u = 0; u < U; ++u)
      s[u] = (__expf(v[u].x) + __expf(v[u].y)) +
             (__expf(v[u].z) + __expf(v[u].w));

    // in-lane max + first-occurrence argmax over 4 elements
    float m[U], lm[U];
    int col[U];
    #pragma unroll
    for (int u = 0; u < U; ++u) {
      float mm = v[u].x; int c = 0;
      if (v[u].y > mm) { mm = v[u].y; c = 1; }
      if (v[u].z > mm) { mm = v[u].z; c = 2; }
      if (v[u].w > mm) { mm = v[u].w; c = 3; }
      m[u] = mm; lm[u] = mm; col[u] = (hl << 2) + c;
    }

    // ONE interleaved half-wave shuffle pass: 2U independent chains
    #pragma unroll
    for (int off = 1; off <= 16; off <<= 1) {
      #pragma unroll
      for (int u = 0; u < U; ++u) m[u] = fmaxf(m[u], __shfl_xor(m[u], off));
      #pragma unroll
      for (int u = 0; u < U; ++u) s[u] += __shfl_xor(s[u], off);
    }

    // first-occurrence argmax via ballot (lowest flagged lane in this half)
    int wcol[U];
    #pragma unroll
    for (int u = 0; u < U; ++u) {
      const unsigned long long b = __ballot(lm[u] == m[u]);
      const unsigned slice = (unsigned)(b >> (half << 5));
      const int srcl = (half << 5) + (__ffs(slice) - 1);
      wcol[u] = __shfl(col[u], srcl);
    }

    #pragma unroll
    for (int u = 0; u < U; ++u) {
      if ((p0 + u) < npairs && hl == 0) {
        const float conf = __expf(m[u]) / s[u];    // = max(softmax(row))
        int bin = (int)ceilf(conf * 10.0f) - 1;    // (k/10,(k+1)/10] -> k
        bin = min(max(bin, 0), NBINS - 1);
        const unsigned long long acc = (tg[u] == wcol[u]) ? 1ull : 0ull;
        const unsigned long long confq =
            (unsigned long long)((double)conf * 4294967296.0);
        atomicAdd(&sbins[bin], 1ull);
        atomicAdd(&sbins[NBINS + bin], confq);
        atomicAdd(&sbins[2 * NBINS + bin], acc);
      }
    }
  }

  // odd-N leftover row (not hit for N=262144; kept for generality)
  if ((N & 1) && wid == 0 && half == 0) {
    const int row = N - 1;
    const float4 x = *reinterpret_cast<const float4*>(
        logits + (size_t)row * C + hl * 4);
    float m = x.x; int c = 0;
    if (x.y > m) { m = x.y; c = 1; }
    if (x.z > m) { m = x.z; c = 2; }
    if (x.w > m) { m = x.w; c = 3; }
    const float lmv = m;
    const int col = (hl << 2) + c;
    float s = (__expf(x.x) + __expf(x.y)) + (__expf(x.z) + __expf(x.w));
    #pragma unroll
    for (int off = 1; off <= 16; off <<= 1) {
      m = fmaxf(m, __shfl_xor(m, off));
      s += __shfl_xor(s, off);
    }
    const unsigned long long b = __ballot(lmv == m);
    const int srcl = __ffs((unsigned)b) - 1;
    const int wcol = __shfl(col, srcl);
    if (hl == 0) {
      const float conf = __expf(m) / s;
      int bin = (int)ceilf(conf * 10.0f) - 1;
      bin = min(max(bin, 0), NBINS - 1);
      const unsigned long long acc = (targets[row] == wcol) ? 1ull : 0ull;
      const unsigned long long confq =
          (unsigned long long)((double)conf * 4294967296.0);
      atomicAdd(&sbins[bin], 1ull);
      atomicAdd(&sbins[NBINS + bin], confq);
      atomicAdd(&sbins[2 * NBINS + bin], acc);
    }
  }

  // flush block partials into this block's replica (low-contention atomics)
  __syncthreads();
  unsigned long long* rep =
      gbins + (size_t)(blockIdx.x & (NREP - 1)) * REPSTRIDE;
  for (int i = tid; i < 3 * NBINS; i += blockDim.x) {
    unsigned long long vv = sbins[i];
    if (vv) atomicAdd(&rep[i], vv);
  }
}

__global__ void ece_final_kernel(const unsigned long long* __restrict__ gbins,
                                 float* __restrict__ out, int N) {
  __shared__ unsigned long long tot[3 * NBINS];
  const int t = threadIdx.x;  // 64 threads
  if (t < 3 * NBINS) {
    unsigned long long s = 0ull;
    #pragma unroll 8
    for (int r = 0; r < NREP; ++r) s += gbins[(size_t)r * REPSTRIDE + t];
    tot[t] = s;
  }
  __syncthreads();
  float per = 0.0f;
  if (t < NBINS) {
    const double cnt = (double)tot[t];
    const double sc = (double)tot[NBINS + t] * (1.0 / 4294967296.0);
    const double sa = (double)tot[2 * NBINS + t];
    const double safe = cnt > 0.0 ? cnt : 1.0;
    const double avg_c = sc / safe;
    const double avg_a = sa / safe;
    const double prop = cnt / (double)N;
    per = (cnt > 0.0) ? (float)(fabs(avg_c - avg_a) * prop) : 0.0f;
  }
  #pragma unroll
  for (int off = 1; off < 16; off <<= 1) per += __shfl_xor(per, off);
  if (t == 0) out[0] = per;
}

extern "C" void kernel_launch(void* const* d_in, const int* in_sizes, int n_in,
                              void* d_out, int out_size, void* d_ws, size_t ws_size,
                              hipStream_t stream) {
  const float* logits = (const float*)d_in[0];
  const int* targets = (const int*)d_in[1];
  float* out = (float*)d_out;
  unsigned long long* gbins = (unsigned long long*)d_ws;

  const int N = in_sizes[1];  // 262144 rows

  // zero all replicas (NREP * REPSTRIDE u64 = 16 KB)
  hipMemsetAsync(gbins, 0, NREP * REPSTRIDE * sizeof(unsigned long long),
                 stream);

  const int block = 256;  // 4 waves/block
  const int wavesPerBlock = block / 64;
  const int npairs = N >> 1;
  // one-shot: each wave gets exactly U pairs (N=262144 -> grid 4096, no loop)
  int grid = (npairs + wavesPerBlock * U - 1) / (wavesPerBlock * U);
  if (grid < 1) grid = 1;

  ece_main_kernel<<<grid, block, 0, stream>>>(logits, targets, gbins, N);
  ece_final_kernel<<<1, 64, 0, stream>>>(gbins, out, N);
}

// Round 10
// 39.436 us; speedup vs baseline: 1.0382x; 1.0382x over previous
//
#include <hip/hip_runtime.h>
#include <hip/hip_bf16.h>

#define NBINS 10
#define C 128
#define U 8           // pairs per wave (one-shot: all loads issued up front)
#define NREP 64       // gbins replicas (de-contend device-scope atomics)
#define REPSTRIDE 32  // u64 slots per replica (30 used, padded)

// d_ws layout: NREP replicas of [0..9] counts, [10..19] sum_conf (32.32 fixed),
//              [20..29] sum_acc  -- each replica REPSTRIDE u64 slots.

__global__ __launch_bounds__(256) void ece_main_kernel(
    const float* __restrict__ logits, const int* __restrict__ targets,
    unsigned long long* __restrict__ gbins, int N) {
  __shared__ unsigned long long sbins[3 * NBINS];
  const int tid = threadIdx.x;
  for (int i = tid; i < 3 * NBINS; i += blockDim.x) sbins[i] = 0ull;
  __syncthreads();

  const int lane = tid & 63;
  const int half = lane >> 5;   // which row of each pair this lane works on
  const int hl = lane & 31;     // lane index within the 32-lane half
  const int wavesPerBlock = blockDim.x >> 6;
  const int wid = blockIdx.x * wavesPerBlock + (tid >> 6);
  const int nwaves = gridDim.x * wavesPerBlock;

  const int npairs = N >> 1;

  for (int p0 = wid * U; p0 < npairs; p0 += nwaves * U) {
    float4 v[U];
    int tg[U];
    const bool full = (p0 + U) <= npairs;

    if (full) {
      // FAST PATH (every wave at N=262144): one base, constant offsets ->
      // compiler folds to immediate-offset global_load_dwordx4, no clamps.
      const float* base = logits + ((size_t)p0 * 2 + half) * C + (hl << 2);
      #pragma unroll
      for (int u = 0; u < U; ++u)
        v[u] = *reinterpret_cast<const float4*>(base + u * (2 * C));
      if (hl == 0) {
        const int* tb = targets + p0 * 2 + half;
        #pragma unroll
        for (int u = 0; u < U; ++u) tg[u] = tb[2 * u];
      }
    } else {
      #pragma unroll
      for (int u = 0; u < U; ++u) {
        const int p = p0 + u;
        const int pc = p < npairs ? p : npairs - 1;
        v[u] = *reinterpret_cast<const float4*>(
            logits + (size_t)pc * (2 * C) + half * C + (hl << 2));
      }
      if (hl == 0) {
        #pragma unroll
        for (int u = 0; u < U; ++u) {
          const int p = p0 + u;
          const int pc = p < npairs ? p : npairs - 1;
          tg[u] = targets[pc * 2 + half];
        }
      }
    }

    // exps issue as loads land (no max-subtract: |logit| <~ 6 for N(0,1);
    // conf = exp(m)/sum(exp(x)) is mathematically identical)
    float s[U];
    #pragma unroll
    for (int u = 0; u < U; ++u)
      s[u] = (__expf(v[u].x) + __expf(v[u].y)) +
             (__expf(v[u].z) + __expf(v[u].w));

    // in-lane max + first-occurrence argmax over 4 elements
    float m[U], lm[U];
    int col[U];
    #pragma unroll
    for (int u = 0; u < U; ++u) {
      float mm = v[u].x; int c = 0;
      if (v[u].y > mm) { mm = v[u].y; c = 1; }
      if (v[u].z > mm) { mm = v[u].z; c = 2; }
      if (v[u].w > mm) { mm = v[u].w; c = 3; }
      m[u] = mm; lm[u] = mm; col[u] = (hl << 2) + c;
    }

    // ONE interleaved half-wave shuffle pass: 2U independent chains
    #pragma unroll
    for (int off = 1; off <= 16; off <<= 1) {
      #pragma unroll
      for (int u = 0; u < U; ++u) m[u] = fmaxf(m[u], __shfl_xor(m[u], off));
      #pragma unroll
      for (int u = 0; u < U; ++u) s[u] += __shfl_xor(s[u], off);
    }

    // first-occurrence argmax via ballot (lowest flagged lane in this half)
    int wcol[U];
    #pragma unroll
    for (int u = 0; u < U; ++u) {
      const unsigned long long b = __ballot(lm[u] == m[u]);
      const unsigned slice = (unsigned)(b >> (half << 5));
      const int srcl = (half << 5) + (__ffs(slice) - 1);
      wcol[u] = __shfl(col[u], srcl);
    }

    if (hl == 0) {
      #pragma unroll
      for (int u = 0; u < U; ++u) {
        if (full || (p0 + u) < npairs) {
          const float conf = __expf(m[u]) / s[u];  // = max(softmax(row))
          int bin = (int)ceilf(conf * 10.0f) - 1;  // (k/10,(k+1)/10] -> k
          bin = min(max(bin, 0), NBINS - 1);
          const unsigned long long acc = (tg[u] == wcol[u]) ? 1ull : 0ull;
          const unsigned long long confq =
              (unsigned long long)((double)conf * 4294967296.0);
          atomicAdd(&sbins[bin], 1ull);
          atomicAdd(&sbins[NBINS + bin], confq);
          atomicAdd(&sbins[2 * NBINS + bin], acc);
        }
      }
    }
  }

  // odd-N leftover row (not hit for N=262144; kept for generality)
  if ((N & 1) && wid == 0 && half == 0) {
    const int row = N - 1;
    const float4 x = *reinterpret_cast<const float4*>(
        logits + (size_t)row * C + (hl << 2));
    float m = x.x; int c = 0;
    if (x.y > m) { m = x.y; c = 1; }
    if (x.z > m) { m = x.z; c = 2; }
    if (x.w > m) { m = x.w; c = 3; }
    const float lmv = m;
    const int col = (hl << 2) + c;
    float s = (__expf(x.x) + __expf(x.y)) + (__expf(x.z) + __expf(x.w));
    #pragma unroll
    for (int off = 1; off <= 16; off <<= 1) {
      m = fmaxf(m, __shfl_xor(m, off));
      s += __shfl_xor(s, off);
    }
    const unsigned long long b = __ballot(lmv == m);
    const int srcl = __ffs((unsigned)b) - 1;
    const int wcol = __shfl(col, srcl);
    if (hl == 0) {
      const float conf = __expf(m) / s;
      int bin = (int)ceilf(conf * 10.0f) - 1;
      bin = min(max(bin, 0), NBINS - 1);
      const unsigned long long acc = (targets[row] == wcol) ? 1ull : 0ull;
      const unsigned long long confq =
          (unsigned long long)((double)conf * 4294967296.0);
      atomicAdd(&sbins[bin], 1ull);
      atomicAdd(&sbins[NBINS + bin], confq);
      atomicAdd(&sbins[2 * NBINS + bin], acc);
    }
  }

  // flush block partials into this block's replica (low-contention atomics)
  __syncthreads();
  unsigned long long* rep =
      gbins + (size_t)(blockIdx.x & (NREP - 1)) * REPSTRIDE;
  for (int i = tid; i < 3 * NBINS; i += blockDim.x) {
    unsigned long long vv = sbins[i];
    if (vv) atomicAdd(&rep[i], vv);
  }
}

__global__ void ece_final_kernel(const unsigned long long* __restrict__ gbins,
                                 float* __restrict__ out, int N) {
  __shared__ unsigned long long tot[3 * NBINS];
  const int t = threadIdx.x;  // 64 threads
  if (t < 3 * NBINS) {
    unsigned long long s = 0ull;
    #pragma unroll 8
    for (int r = 0; r < NREP; ++r) s += gbins[(size_t)r * REPSTRIDE + t];
    tot[t] = s;
  }
  __syncthreads();
  float per = 0.0f;
  if (t < NBINS) {
    const double cnt = (double)tot[t];
    const double sc = (double)tot[NBINS + t] * (1.0 / 4294967296.0);
    const double sa = (double)tot[2 * NBINS + t];
    const double safe = cnt > 0.0 ? cnt : 1.0;
    const double avg_c = sc / safe;
    const double avg_a = sa / safe;
    const double prop = cnt / (double)N;
    per = (cnt > 0.0) ? (float)(fabs(avg_c - avg_a) * prop) : 0.0f;
  }
  #pragma unroll
  for (int off = 1; off < 16; off <<= 1) per += __shfl_xor(per, off);
  if (t == 0) out[0] = per;
}

extern "C" void kernel_launch(void* const* d_in, const int* in_sizes, int n_in,
                              void* d_out, int out_size, void* d_ws, size_t ws_size,
                              hipStream_t stream) {
  const float* logits = (const float*)d_in[0];
  const int* targets = (const int*)d_in[1];
  float* out = (float*)d_out;
  unsigned long long* gbins = (unsigned long long*)d_ws;

  const int N = in_sizes[1];  // 262144 rows

  // zero all replicas (NREP * REPSTRIDE u64 = 16 KB)
  hipMemsetAsync(gbins, 0, NREP * REPSTRIDE * sizeof(unsigned long long),
                 stream);

  const int block = 256;  // 4 waves/block
  const int wavesPerBlock = block / 64;
  const int npairs = N >> 1;
  // one-shot: each wave gets exactly U pairs (N=262144 -> grid 4096, no loop)
  int grid = (npairs + wavesPerBlock * U - 1) / (wavesPerBlock * U);
  if (grid < 1) grid = 1;

  ece_main_kernel<<<grid, block, 0, stream>>>(logits, targets, gbins, N);
  ece_final_kernel<<<1, 64, 0, stream>>>(gbins, out, N);
}